// Round 9
// baseline (89.032 us; speedup 1.0000x reference)
//
#include <hip/hip_runtime.h>
#include <math.h>

// Problem constants
#define PP 2048
#define KK 8
#define BB 4
#define NN 16384                 // KK*PP points per cloud
#define CSTRIDE 16392            // KK*(PP+1): stride between coordinate planes
#define BSTRIDE 49176            // 3*CSTRIDE: stride between batches

// MFMA tiling (32x32x16 shape)
#define FRAGS 8                  // a-fragments per wave: 256 rows/wave
#define ROWS_PER_BLOCK 1024      // 4 waves * 256
#define ROWBLOCKS 16             // 16384 / 1024
#define NSLICES 8                // b-dimension split
#define SLICEPTS 2048            // NN / NSLICES
#define CHUNKPTS 1024            // staged b-points per chunk (32 KB LDS)
#define TILES 32                 // CHUNKPTS / 32

typedef _Float16 f16;
typedef __attribute__((ext_vector_type(8))) _Float16 f16x8;
typedef __attribute__((ext_vector_type(16))) float f32x16;

// MFMA forced into arch VGPRs ("v" constraints) so the min-fold reads the
// result without v_accvgpr moves. volatile: keeps all asm in program order —
// the depth-3 rotation below guarantees >=32 issue-cycles between each MFMA
// and the first VALU read of its destination (covers the no-interlock hazard).
__device__ __forceinline__ f32x16 mfma_v(f16x8 a, f16x8 b, f32x16 c) {
    f32x16 d;
    asm volatile("v_mfma_f32_32x32x16_f16 %0, %1, %2, %3"
                 : "=v"(d) : "v"(a), "v"(b), "v"(c));
    return d;
}

__device__ __forceinline__ float min3a(float a, float b, float c) {
    float d;
    asm volatile("v_min3_f32 %0, %1, %2, %3" : "=v"(d) : "v"(a), "v"(b), "v"(c));
    return d;
}

// Fold 16 D values into running min (8 x v_min3_f32, ordered asm).
__device__ __forceinline__ void fold16(const f32x16& d, float& a) {
    float m0 = min3a(d[0],  d[1],  d[2]);
    float m1 = min3a(d[3],  d[4],  d[5]);
    float m2 = min3a(d[6],  d[7],  d[8]);
    float m3 = min3a(d[9],  d[10], d[11]);
    float m4 = min3a(d[12], d[13], d[14]);
    float n0 = min3a(m0, m1, m2);
    float n1 = min3a(m3, m4, d[15]);
    a = min3a(a, n0, n1);
}

__global__ __launch_bounds__(256) void init_min_kernel(unsigned* __restrict__ mins) {
    int i = blockIdx.x * 256 + threadIdx.x;
    mins[i] = 0x7F7FFFFFu;       // FLT_MAX bit pattern
}

// MFMA chamfer kernel, both directions in one dispatch (blockIdx.z = dir*BB + b).
// t = 0.5*|b|^2 - a.b via f16 hi/lo split in 11 K-slots:
//   k0-2: b_hi * -a_hi   k3-5: b_lo * -a_hi   k6-8: b_hi * -a_lo
//   k9: bsq_hi * 1       k10: bsq_lo * 1      k11-15: 0
// d2 = max(0, |a|^2 + 2*min_b t); slices combined via atomicMin on float bits.
__global__ __launch_bounds__(256, 2) void chamfer_mfma_kernel(
        const float* __restrict__ pred, const float* __restrict__ tgt,
        unsigned* __restrict__ mins) {
    // 2 k-group regions x CHUNKPTS x 16B = 32 KB.
    __shared__ f16x8 karr[2 * CHUNKPTS];

    const int tid  = threadIdx.x;
    const int lane = tid & 63;
    const int wave = tid >> 6;
    const int col  = lane & 31;       // a-point col / b-row within tile
    const int g2   = lane >> 5;       // k-group (slots 0-7 vs 8-15)
    const int dir  = blockIdx.z >> 2;
    const int b    = blockIdx.z & 3;
    const int slice = blockIdx.y;
    const int rowblock = blockIdx.x;

    const float* __restrict__ Apts = dir ? tgt : pred;
    const float* __restrict__ Bpts = dir ? pred : tgt;
    unsigned* __restrict__ minOut = mins + dir * BB * NN;

    // Prologue: per-lane B-operand fragments for this wave's 256 a-points.
    f16x8 bop[FRAGS];
    float asq[FRAGS], acc[FRAGS];
    const int rbase = rowblock * ROWS_PER_BLOCK + wave * (FRAGS * 32);
#pragma unroll
    for (int f = 0; f < FRAGS; ++f) {
        int r = rbase + f * 32 + col;
        int abase = b * BSTRIDE + (r >> 11) * (PP + 1) + (r & (PP - 1));
        float ax = Apts[abase];
        float ay = Apts[abase + CSTRIDE];
        float az = Apts[abase + 2 * CSTRIDE];
        asq[f] = fmaf(ax, ax, fmaf(ay, ay, az * az));
        acc[f] = 1.0e30f;
        f16 h0 = (f16)ax, h1 = (f16)ay, h2 = (f16)az;
        f16 l0 = (f16)(ax - (float)h0);
        f16 l1 = (f16)(ay - (float)h1);
        f16 l2 = (f16)(az - (float)h2);
        f16x8 v;
#pragma unroll
        for (int j = 0; j < 8; ++j) v[j] = (f16)0.f;
        if (g2 == 0) {
            v[0] = -h0; v[1] = -h1; v[2] = -h2;
            v[3] = -h0; v[4] = -h1; v[5] = -h2;
            v[6] = -l0; v[7] = -l1;
        } else {
            v[0] = -l2; v[1] = (f16)1.f; v[2] = (f16)1.f;
        }
        bop[f] = v;
    }

    f32x16 Z16;
#pragma unroll
    for (int j = 0; j < 16; ++j) Z16[j] = 0.f;

    for (int c = 0; c < SLICEPTS / CHUNKPTS; ++c) {
        __syncthreads();
        // Stage CHUNKPTS b-points: A-operand records for k-slots 0-7 and 8-15.
#pragma unroll
        for (int q = 0; q < 4; ++q) {
            int p  = tid + q * 256;
            int cj = slice * SLICEPTS + c * CHUNKPTS + p;
            int gb = b * BSTRIDE + (cj >> 11) * (PP + 1) + (cj & (PP - 1));
            float x = Bpts[gb];
            float y = Bpts[gb + CSTRIDE];
            float z = Bpts[gb + 2 * CSTRIDE];
            f16 h0 = (f16)x, h1 = (f16)y, h2 = (f16)z;
            f16 l0 = (f16)(x - (float)h0);
            f16 l1 = (f16)(y - (float)h1);
            f16 l2 = (f16)(z - (float)h2);
            float bsq = 0.5f * fmaf(x, x, fmaf(y, y, z * z));
            f16 sh = (f16)bsq;
            f16 sl = (f16)(bsq - (float)sh);
            f16x8 lo;
            lo[0] = h0; lo[1] = h1; lo[2] = h2;
            lo[3] = l0; lo[4] = l1; lo[5] = l2;
            lo[6] = h0; lo[7] = h1;
            f16x8 hi;
#pragma unroll
            for (int j = 0; j < 8; ++j) hi[j] = (f16)0.f;
            hi[0] = h2; hi[1] = sh; hi[2] = sl;
            karr[p] = lo;
            karr[CHUNKPTS + p] = hi;
        }
        __syncthreads();

        // Inner loop, depth-3 D rotation in pure VGPR asm: every fold is
        // >=2 MFMAs (or >=16 min3) after its producer -> hazard-safe.
        const f16x8* kptr = karr + g2 * CHUNKPTS + col;
#pragma unroll 2
        for (int t = 0; t < TILES; ++t) {
            f16x8 af = kptr[t * 32];
            f32x16 d0, d1, d2;
            d0 = mfma_v(af, bop[0], Z16);
            d1 = mfma_v(af, bop[1], Z16);
            d2 = mfma_v(af, bop[2], Z16);
            fold16(d0, acc[0]);
            d0 = mfma_v(af, bop[3], Z16);
            fold16(d1, acc[1]);
            d1 = mfma_v(af, bop[4], Z16);
            fold16(d2, acc[2]);
            d2 = mfma_v(af, bop[5], Z16);
            fold16(d0, acc[3]);
            d0 = mfma_v(af, bop[6], Z16);
            fold16(d1, acc[4]);
            d1 = mfma_v(af, bop[7], Z16);
            fold16(d2, acc[5]);
            fold16(d0, acc[6]);
            fold16(d1, acc[7]);
        }
    }

    // Epilogue: b-rows split across lane>>5 only; one shfl then atomic.
#pragma unroll
    for (int f = 0; f < FRAGS; ++f) {
        float m = acc[f];
        m = fminf(m, __shfl_xor(m, 32));
        if (lane < 32) {
            float d2v = fmaxf(fmaf(2.0f, m, asq[f]), 0.0f);
            atomicMin(&minOut[b * NN + rbase + f * 32 + col], __float_as_uint(d2v));
        }
    }
}

// Single-block fused reduction: sum sqrt(mins) + detection loss -> out[0].
__global__ __launch_bounds__(1024) void reduce_final_kernel(
        const unsigned* __restrict__ mins,
        const float* __restrict__ pred, const float* __restrict__ tgt,
        float* __restrict__ out) {
    int tid = threadIdx.x;
    const uint4* m4 = (const uint4*)mins;
    float s = 0.f;
    for (int i = tid; i < (2 * BB * NN) / 4; i += 1024) {
        uint4 u = m4[i];
        s += sqrtf(__uint_as_float(u.x)) + sqrtf(__uint_as_float(u.y)) +
             sqrtf(__uint_as_float(u.z)) + sqrtf(__uint_as_float(u.w));
    }
    // point_cloud_loss = grand_sum / (2 * NN * BB) = / 131072
    float v = s * (1.0f / 131072.0f);
    if (tid < 32) {
        int b = tid >> 3, k = tid & 7;
        int idx = b * BSTRIDE + k * (PP + 1) + PP;
        float z = pred[idx];
        float t = tgt[idx] > 0.5f ? 1.0f : 0.0f;
        v += (fmaxf(z, 0.f) - z * t + log1pf(expf(-fabsf(z)))) * (1.0f / 32.0f);
    }
    __shared__ float red[1024];
    red[tid] = v;
    __syncthreads();
    for (int off = 512; off > 0; off >>= 1) {
        if (tid < off) red[tid] += red[tid + off];
        __syncthreads();
    }
    if (tid == 0) out[0] = red[0];
}

extern "C" void kernel_launch(void* const* d_in, const int* in_sizes, int n_in,
                              void* d_out, int out_size, void* d_ws, size_t ws_size,
                              hipStream_t stream) {
    const float* pred = (const float*)d_in[0];
    const float* tgt  = (const float*)d_in[1];
    float* out = (float*)d_out;

    unsigned* mins = (unsigned*)d_ws;   // 2*BB*NN u32 = 512 KB

    init_min_kernel<<<2 * BB * NN / 256, 256, 0, stream>>>(mins);
    dim3 grid(ROWBLOCKS, NSLICES, 2 * BB);
    chamfer_mfma_kernel<<<grid, 256, 0, stream>>>(pred, tgt, mins);
    reduce_final_kernel<<<1, 1024, 0, stream>>>(mins, pred, tgt, out);
}

// Round 10
// 83.532 us; speedup vs baseline: 1.0658x; 1.0658x over previous
//
#include <hip/hip_runtime.h>
#include <math.h>

// Problem constants
#define PP 2048
#define KK 8
#define BB 4
#define NN 16384                 // KK*PP points per cloud
#define CSTRIDE 16392            // KK*(PP+1): stride between coordinate planes
#define BSTRIDE 49176            // 3*CSTRIDE: stride between batches

// MFMA tiling (32x32x16 shape)
#define FRAGS 8                  // a-fragments per wave: 256 rows/wave
#define ROWS_PER_BLOCK 1024      // 4 waves * 256
#define ROWBLOCKS 16             // 16384 / 1024
#define NSLICES 8                // b-dimension split
#define SLICEPTS 2048            // NN / NSLICES
#define CHUNKPTS 1024            // staged b-points per chunk (32 KB LDS)
#define TILES 32                 // CHUNKPTS / 32
#define RBLK 64                  // reduce blocks

typedef _Float16 f16;
typedef __attribute__((ext_vector_type(8))) _Float16 f16x8;
typedef __attribute__((ext_vector_type(16))) float f32x16;

// MFMA with INLINE-CONSTANT 0 as the C operand: no C register tuple exists,
// so there is no per-MFMA zero-copy into the destination (the parasitic
// ~16 VALU moves/MFMA seen in rounds 6/8/9). D constrained to VGPRs.
// volatile: pins the hand-written depth-3 rotation order (proven hazard-safe
// in round 9: >=2 MFMAs or >=16 min3 between each MFMA and its first read).
__device__ __forceinline__ f32x16 mfma_z(f16x8 a, f16x8 b) {
    f32x16 d;
    asm volatile("v_mfma_f32_32x32x16_f16 %0, %1, %2, 0"
                 : "=v"(d) : "v"(a), "v"(b));
    return d;
}

__device__ __forceinline__ float min3f(float a, float b, float c) {
    return fminf(fminf(a, b), c);   // -> v_min3_f32
}

// Fold 16 D values into running min (8 x v_min3_f32).
__device__ __forceinline__ void fold16(const f32x16& d, float& a) {
    float m0 = min3f(d[0],  d[1],  d[2]);
    float m1 = min3f(d[3],  d[4],  d[5]);
    float m2 = min3f(d[6],  d[7],  d[8]);
    float m3 = min3f(d[9],  d[10], d[11]);
    float m4 = min3f(d[12], d[13], d[14]);
    float n0 = min3f(m0, m1, m2);
    float n1 = min3f(m3, m4, d[15]);
    a = min3f(a, n0, n1);
}

__global__ __launch_bounds__(256) void init_min_kernel(
        unsigned* __restrict__ mins, unsigned long long* __restrict__ sum,
        unsigned* __restrict__ ticket) {
    int i = blockIdx.x * 256 + threadIdx.x;
    mins[i] = 0x7F7FFFFFu;       // FLT_MAX bit pattern
    if (i == 0) { *sum = 0ULL; *ticket = 0u; }
}

// MFMA chamfer kernel, both directions in one dispatch (blockIdx.z = dir*BB + b).
// t = 0.5*|b|^2 - a.b via f16 hi/lo split in 11 K-slots:
//   k0-2: b_hi * -a_hi   k3-5: b_lo * -a_hi   k6-8: b_hi * -a_lo
//   k9: bsq_hi * 1       k10: bsq_lo * 1      k11-15: 0
// d2 = max(0, |a|^2 + 2*min_b t); slices combined via atomicMin on float bits.
__global__ __launch_bounds__(256, 2) void chamfer_mfma_kernel(
        const float* __restrict__ pred, const float* __restrict__ tgt,
        unsigned* __restrict__ mins) {
    // 2 k-group regions x CHUNKPTS x 16B = 32 KB.
    __shared__ f16x8 karr[2 * CHUNKPTS];

    const int tid  = threadIdx.x;
    const int lane = tid & 63;
    const int wave = tid >> 6;
    const int col  = lane & 31;       // a-point col / b-row within tile
    const int g2   = lane >> 5;       // k-group (slots 0-7 vs 8-15)
    const int dir  = blockIdx.z >> 2;
    const int b    = blockIdx.z & 3;
    const int slice = blockIdx.y;
    const int rowblock = blockIdx.x;

    const float* __restrict__ Apts = dir ? tgt : pred;
    const float* __restrict__ Bpts = dir ? pred : tgt;
    unsigned* __restrict__ minOut = mins + dir * BB * NN;

    // Prologue: per-lane B-operand fragments for this wave's 256 a-points.
    f16x8 bop[FRAGS];
    float asq[FRAGS], acc[FRAGS];
    const int rbase = rowblock * ROWS_PER_BLOCK + wave * (FRAGS * 32);
#pragma unroll
    for (int f = 0; f < FRAGS; ++f) {
        int r = rbase + f * 32 + col;
        int abase = b * BSTRIDE + (r >> 11) * (PP + 1) + (r & (PP - 1));
        float ax = Apts[abase];
        float ay = Apts[abase + CSTRIDE];
        float az = Apts[abase + 2 * CSTRIDE];
        asq[f] = fmaf(ax, ax, fmaf(ay, ay, az * az));
        acc[f] = 1.0e30f;
        f16 h0 = (f16)ax, h1 = (f16)ay, h2 = (f16)az;
        f16 l0 = (f16)(ax - (float)h0);
        f16 l1 = (f16)(ay - (float)h1);
        f16 l2 = (f16)(az - (float)h2);
        f16x8 v;
#pragma unroll
        for (int j = 0; j < 8; ++j) v[j] = (f16)0.f;
        if (g2 == 0) {
            v[0] = -h0; v[1] = -h1; v[2] = -h2;
            v[3] = -h0; v[4] = -h1; v[5] = -h2;
            v[6] = -l0; v[7] = -l1;
        } else {
            v[0] = -l2; v[1] = (f16)1.f; v[2] = (f16)1.f;
        }
        bop[f] = v;
    }

    for (int c = 0; c < SLICEPTS / CHUNKPTS; ++c) {
        __syncthreads();
        // Stage CHUNKPTS b-points: A-operand records for k-slots 0-7 and 8-15.
#pragma unroll
        for (int q = 0; q < 4; ++q) {
            int p  = tid + q * 256;
            int cj = slice * SLICEPTS + c * CHUNKPTS + p;
            int gb = b * BSTRIDE + (cj >> 11) * (PP + 1) + (cj & (PP - 1));
            float x = Bpts[gb];
            float y = Bpts[gb + CSTRIDE];
            float z = Bpts[gb + 2 * CSTRIDE];
            f16 h0 = (f16)x, h1 = (f16)y, h2 = (f16)z;
            f16 l0 = (f16)(x - (float)h0);
            f16 l1 = (f16)(y - (float)h1);
            f16 l2 = (f16)(z - (float)h2);
            float bsq = 0.5f * fmaf(x, x, fmaf(y, y, z * z));
            f16 sh = (f16)bsq;
            f16 sl = (f16)(bsq - (float)sh);
            f16x8 lo;
            lo[0] = h0; lo[1] = h1; lo[2] = h2;
            lo[3] = l0; lo[4] = l1; lo[5] = l2;
            lo[6] = h0; lo[7] = h1;
            f16x8 hi;
#pragma unroll
            for (int j = 0; j < 8; ++j) hi[j] = (f16)0.f;
            hi[0] = h2; hi[1] = sh; hi[2] = sl;
            karr[p] = lo;
            karr[CHUNKPTS + p] = hi;
        }
        __syncthreads();

        // Inner loop, depth-3 D rotation: every fold >=2 MFMAs (or >=16 min3)
        // after its producer; no C operand -> no zero-copy VALU.
        const f16x8* kptr = karr + g2 * CHUNKPTS + col;
#pragma unroll 2
        for (int t = 0; t < TILES; ++t) {
            f16x8 af = kptr[t * 32];
            f32x16 d0, d1, d2;
            d0 = mfma_z(af, bop[0]);
            d1 = mfma_z(af, bop[1]);
            d2 = mfma_z(af, bop[2]);
            fold16(d0, acc[0]);
            d0 = mfma_z(af, bop[3]);
            fold16(d1, acc[1]);
            d1 = mfma_z(af, bop[4]);
            fold16(d2, acc[2]);
            d2 = mfma_z(af, bop[5]);
            fold16(d0, acc[3]);
            d0 = mfma_z(af, bop[6]);
            fold16(d1, acc[4]);
            d1 = mfma_z(af, bop[7]);
            fold16(d2, acc[5]);
            fold16(d0, acc[6]);
            fold16(d1, acc[7]);
        }
    }

    // Epilogue: b-rows split across lane>>5 only; one shfl then atomic.
#pragma unroll
    for (int f = 0; f < FRAGS; ++f) {
        float m = acc[f];
        m = fminf(m, __shfl_xor(m, 32));
        if (lane < 32) {
            float d2v = fmaxf(fmaf(2.0f, m, asq[f]), 0.0f);
            atomicMin(&minOut[b * NN + rbase + f * 32 + col], __float_as_uint(d2v));
        }
    }
}

// Multi-block deterministic reduction: per-block partial sums of sqrt(mins)
// accumulated in fixed-point (2^-40) via integer atomics (order-independent),
// last-arriving block computes detection loss + final scalar.
__global__ __launch_bounds__(256) void reduce_kernel(
        const unsigned* __restrict__ mins, unsigned long long* __restrict__ sum,
        unsigned* __restrict__ ticket,
        const float* __restrict__ pred, const float* __restrict__ tgt,
        float* __restrict__ out) {
    int tid = threadIdx.x;
    const uint4* m4 = (const uint4*)mins;
    float s = 0.f;
    for (int i = blockIdx.x * 256 + tid; i < (2 * BB * NN) / 4; i += RBLK * 256) {
        uint4 u = m4[i];
        s += sqrtf(__uint_as_float(u.x)) + sqrtf(__uint_as_float(u.y)) +
             sqrtf(__uint_as_float(u.z)) + sqrtf(__uint_as_float(u.w));
    }
    __shared__ float red[256];
    red[tid] = s;
    __syncthreads();
    for (int off = 128; off > 0; off >>= 1) {
        if (tid < off) red[tid] += red[tid + off];
        __syncthreads();
    }
    if (tid == 0) {
        unsigned long long fx = (unsigned long long)((double)red[0] * 1099511627776.0);
        atomicAdd(sum, fx);
        __threadfence();
        unsigned prev = atomicAdd(ticket, 1u);
        if (prev == RBLK - 1) {
            unsigned long long tot = atomicAdd(sum, 0ULL);
            // point_cloud_loss = grand_sum / (2 * NN * BB) = / 131072
            float v = (float)((double)tot * (1.0 / 1099511627776.0) * (1.0 / 131072.0));
            float det = 0.f;
            for (int j = 0; j < 32; ++j) {
                int bb = j >> 3, k = j & 7;
                int idx = bb * BSTRIDE + k * (PP + 1) + PP;
                float z = pred[idx];
                float t = tgt[idx] > 0.5f ? 1.0f : 0.0f;
                det += fmaxf(z, 0.f) - z * t + log1pf(expf(-fabsf(z)));
            }
            out[0] = v + det * (1.0f / 32.0f);
        }
    }
}

extern "C" void kernel_launch(void* const* d_in, const int* in_sizes, int n_in,
                              void* d_out, int out_size, void* d_ws, size_t ws_size,
                              hipStream_t stream) {
    const float* pred = (const float*)d_in[0];
    const float* tgt  = (const float*)d_in[1];
    float* out = (float*)d_out;

    unsigned* mins = (unsigned*)d_ws;                                   // 512 KB
    unsigned long long* sum = (unsigned long long*)((char*)d_ws + 2 * BB * NN * 4);
    unsigned* ticket = (unsigned*)((char*)d_ws + 2 * BB * NN * 4 + 8);

    init_min_kernel<<<2 * BB * NN / 256, 256, 0, stream>>>(mins, sum, ticket);
    dim3 grid(ROWBLOCKS, NSLICES, 2 * BB);
    chamfer_mfma_kernel<<<grid, 256, 0, stream>>>(pred, tgt, mins);
    reduce_kernel<<<RBLK, 256, 0, stream>>>(mins, sum, ticket, pred, tgt, out);
}